// Round 2
// baseline (249.349 us; speedup 1.0000x reference)
//
#include <hip/hip_runtime.h>

typedef _Float16 half8 __attribute__((ext_vector_type(8)));
typedef float f32x4 __attribute__((ext_vector_type(4)));

#define NBATCH 2048
#define NA 64
#define SA 128
#define HID 256

// LDS: R0 = 16384 halves (32 KB), ATT = 4096 halves (8 KB) -> 40960 B total
#define R0_HALVES 16384
#define SMEM_BYTES 40960

// packed fp16 weight offsets (halves) inside d_ws
#define W_ENC1 0
#define W_ENC2 (W_ENC1 + 128 * 256)
#define W_ATTN (W_ENC2 + 256 * 256)
#define W_GC1 (W_ATTN + 256 * 256)
#define W_NN1 (W_GC1 + 128 * 256)
#define W_GC2 (W_NN1 + 128 * 256)
#define W_NN2 (W_GC2 + 256 * 256)

#define MFMA(a, b, cacc) __builtin_amdgcn_mfma_f32_16x16x32_f16((a), (b), (cacc), 0, 0, 0)

// One launch packs all 7 weights into MFMA B-fragment order fp16.
// dst[((kt*16+nt)*64+lane)*8 + j] = W[kt*32 + (lane>>4)*8 + j][nt*16 + (lane&15)]
__global__ void pack_all(const float* __restrict__ e1, const float* __restrict__ e2,
                         const float* __restrict__ aw, const float* __restrict__ g1,
                         const float* __restrict__ n1, const float* __restrict__ g2,
                         const float* __restrict__ n2, _Float16* __restrict__ dst) {
  int b = (int)blockIdx.x;
  const float* src;
  int off;
  if (b < 16) { src = e1; off = W_ENC1; }
  else if (b < 48) { src = e2; off = W_ENC2; b -= 16; }
  else if (b < 80) { src = aw; off = W_ATTN; b -= 48; }
  else if (b < 96) { src = g1; off = W_GC1; b -= 80; }
  else if (b < 112) { src = n1; off = W_NN1; b -= 96; }
  else if (b < 144) { src = g2; off = W_GC2; b -= 112; }
  else { src = n2; off = W_NN2; b -= 144; }
  int t = b * 256 + (int)threadIdx.x;
  int lane = t & 63, frag = t >> 6;
  int nt = frag & 15, kt = frag >> 4;
  int g = lane >> 4, c = lane & 15;
  half8 h;
#pragma unroll
  for (int j = 0; j < 8; ++j)
    h[j] = (_Float16)src[(size_t)(kt * 32 + g * 8 + j) * 256 + nt * 16 + c];
  *(half8*)(dst + off + (size_t)t * 8) = h;
}

__global__ __launch_bounds__(256, 3) void dicg_main(
    const float* __restrict__ x, const float* __restrict__ b_enc1,
    const float* __restrict__ b_enc2, const float* __restrict__ b_gc1,
    const float* __restrict__ b_nn1, const float* __restrict__ b_gc2,
    const float* __restrict__ b_nn2, const _Float16* __restrict__ wp,
    float* __restrict__ out, float* __restrict__ attn_out) {
  extern __shared__ _Float16 sm[];
  _Float16* R0 = sm;                 // 32 KB: h1 -> emb -> xg1T -> feat -> fg2T
  _Float16* ATTp = sm + R0_HALVES;   // 8 KB: per-wave q-scratch, then attn A-frags

  const int tid = (int)threadIdx.x;
  const int wv = tid >> 6;   // wave 0..3 (owns output cols 64*wv..+63)
  const int lane = tid & 63;
  const int g = lane >> 4;   // 0..3
  const int c = lane & 15;   // 0..15
  const int bb = (int)blockIdx.x;
  const float* __restrict__ xb = x + (size_t)bb * (NA * SA);

  // ---- fragment-linear LDS loads (conflict-free: lane*16B contiguous) ----
  // A-frag region for M[64][K]: frag f=kt*4+rt; data M[16rt+c][32kt+8g+j]
  auto ldA = [&](const _Float16* p, int kt, int rt) -> half8 {
    return *(const half8*)(p + (kt * 4 + rt) * 512 + lane * 8);
  };
  // B-frag region for M2[64][256]: frag f=kt*16+ct; data M2[32kt+8g+j][16ct+c]
  auto ldB = [&](const _Float16* p, int kt, int ct) -> half8 {
    return *(const half8*)(p + (kt * 16 + ct) * 512 + lane * 8);
  };
  // packed weight B-frag (global, L2-resident)
  auto wfrag = [&](const _Float16* wb, int kt, int ntg) -> half8 {
    return *(const half8*)(wb + ((size_t)(kt * 16 + ntg) * 64 + lane) * 8);
  };
  // A-frag of x straight from global f32
  auto xfrag = [&](int r0, int k0) -> half8 {
    const float* p = xb + (r0 + c) * SA + k0 + g * 8;
    f32x4 u = *(const f32x4*)p;
    f32x4 v = *(const f32x4*)(p + 4);
    half8 h;
    h[0] = (_Float16)u[0]; h[1] = (_Float16)u[1];
    h[2] = (_Float16)u[2]; h[3] = (_Float16)u[3];
    h[4] = (_Float16)v[0]; h[5] = (_Float16)v[1];
    h[6] = (_Float16)v[2]; h[7] = (_Float16)v[3];
    return h;
  };

  // ---- C-layout -> packed-LDS scatter stores ----
  // producer lane holds D[16rt+4g+r][64wv+16nt+c]
  auto stA_val = [&](_Float16* dst, int rt, int nt, int r, float v) {
    int kt = 2 * wv + (nt >> 1);
    int lanep = (2 * (nt & 1) + (c >> 3)) * 16 + 4 * g + r;
    dst[(kt * 4 + rt) * 512 + lanep * 8 + (c & 7)] = (_Float16)v;
  };
  auto stB_val = [&](_Float16* dst, int rt, int nt, int r, float v) {
    int rem = 16 * (rt & 1) + 4 * g + r;
    int fi = (rt >> 1) * 16 + 4 * wv + nt;
    dst[fi * 512 + ((rem >> 3) * 16 + c) * 8 + (rem & 7)] = (_Float16)v;
  };
  // P4 scoresT C-layout: lane holds attn[16wv+c][16rt_s+4g+r]
  auto stATT_val = [&](int rt_s, int r, float v) {
    int rem = 16 * (rt_s & 1) + 4 * g + r;
    int fi = (rt_s >> 1) * 4 + wv;
    ATTp[fi * 512 + ((rem >> 3) * 16 + c) * 8 + (rem & 7)] = (_Float16)v;
  };
  // q chunk C-layout -> per-wave B-frag scratch (slot = ATT frag wv)
  auto stQ_val = [&](int nt2, int r, float v) {
    int lanep = (2 * nt2 + (c >> 3)) * 16 + 4 * g + r;
    ATTp[wv * 512 + lanep * 8 + (c & 7)] = (_Float16)v;
  };

  auto mmA = [&](f32x4(&acc)[4][4], const _Float16* Ap, const _Float16* wb, int nkt) {
    for (int kt = 0; kt < nkt; ++kt) {
      half8 af[4], bf[4];
#pragma unroll
      for (int rt = 0; rt < 4; ++rt) af[rt] = ldA(Ap, kt, rt);
#pragma unroll
      for (int nt = 0; nt < 4; ++nt) bf[nt] = wfrag(wb, kt, 4 * wv + nt);
#pragma unroll
      for (int rt = 0; rt < 4; ++rt)
#pragma unroll
        for (int nt = 0; nt < 4; ++nt) acc[rt][nt] = MFMA(af[rt], bf[nt], acc[rt][nt]);
    }
  };
  auto mm_x = [&](f32x4(&acc)[4][4], const _Float16* wb) {
    for (int kt = 0; kt < 4; ++kt) {
      half8 af[4], bf[4];
#pragma unroll
      for (int rt = 0; rt < 4; ++rt) af[rt] = xfrag(16 * rt, kt * 32);
#pragma unroll
      for (int nt = 0; nt < 4; ++nt) bf[nt] = wfrag(wb, kt, 4 * wv + nt);
#pragma unroll
      for (int rt = 0; rt < 4; ++rt)
#pragma unroll
        for (int nt = 0; nt < 4; ++nt) acc[rt][nt] = MFMA(af[rt], bf[nt], acc[rt][nt]);
    }
  };
  auto mm_att = [&](f32x4(&acc)[4][4]) {
#pragma unroll
    for (int kt = 0; kt < 2; ++kt) {
      half8 af[4], bf[4];
#pragma unroll
      for (int rt = 0; rt < 4; ++rt) af[rt] = ldA(ATTp, kt, rt);
#pragma unroll
      for (int nt = 0; nt < 4; ++nt) bf[nt] = ldB(R0, kt, 4 * wv + nt);
#pragma unroll
      for (int rt = 0; rt < 4; ++rt)
#pragma unroll
        for (int nt = 0; nt < 4; ++nt) acc[rt][nt] = MFMA(af[rt], bf[nt], acc[rt][nt]);
    }
  };

  // ================= P1: h1 = relu(x@enc1+b1) -> R0 (A-packed) =================
  {
    f32x4 acc[4][4]{};
    mm_x(acc, wp + W_ENC1);
#pragma unroll
    for (int nt = 0; nt < 4; ++nt) {
      float bv = b_enc1[64 * wv + 16 * nt + c];
#pragma unroll
      for (int rt = 0; rt < 4; ++rt)
#pragma unroll
        for (int r = 0; r < 4; ++r)
          stA_val(R0, rt, nt, r, fmaxf(acc[rt][nt][r] + bv, 0.f));
    }
  }
  __syncthreads();  // B1
  // ============ P2: emb = relu(h1@enc2+b2), in-place over h1 ============
  {
    f32x4 acc[4][4]{};
    mmA(acc, R0, wp + W_ENC2, 8);
    __syncthreads();  // B2: all h1 reads done
#pragma unroll
    for (int nt = 0; nt < 4; ++nt) {
      float bv = b_enc2[64 * wv + 16 * nt + c];
#pragma unroll
      for (int rt = 0; rt < 4; ++rt)
#pragma unroll
        for (int r = 0; r < 4; ++r)
          stA_val(R0, rt, nt, r, fmaxf(acc[rt][nt][r] + bv, 0.f));
    }
  }
  __syncthreads();  // B3
  // === P3+P4 fused: scoresT = emb @ qT (q via per-wave scratch), softmax ===
  {
    half8 aeK[8];
#pragma unroll
    for (int k2 = 0; k2 < 8; ++k2) aeK[k2] = ldA(R0, k2, wv);  // emb rows of this wave
    f32x4 sc[4]{};
    for (int ktp = 0; ktp < 8; ++ktp) {
      f32x4 q2[2]{};
#pragma unroll
      for (int k2 = 0; k2 < 8; ++k2) {
        q2[0] = MFMA(aeK[k2], wfrag(wp + W_ATTN, k2, 2 * ktp + 0), q2[0]);
        q2[1] = MFMA(aeK[k2], wfrag(wp + W_ATTN, k2, 2 * ktp + 1), q2[1]);
      }
#pragma unroll
      for (int nt2 = 0; nt2 < 2; ++nt2)
#pragma unroll
        for (int r = 0; r < 4; ++r) stQ_val(nt2, r, q2[nt2][r]);
      asm volatile("s_waitcnt lgkmcnt(0)" ::: "memory");
      half8 qb = *(const half8*)(ATTp + wv * 512 + lane * 8);
#pragma unroll
      for (int rt = 0; rt < 4; ++rt) sc[rt] = MFMA(ldA(R0, ktp, rt), qb, sc[rt]);
    }
    // softmax over row (16wv+c); row spread across 4 lanes {g*16+c}
    float m = sc[0][0];
#pragma unroll
    for (int rt = 0; rt < 4; ++rt)
#pragma unroll
      for (int r = 0; r < 4; ++r) m = fmaxf(m, sc[rt][r]);
    m = fmaxf(m, __shfl_xor(m, 16));
    m = fmaxf(m, __shfl_xor(m, 32));
    float e[4][4], s = 0.f;
#pragma unroll
    for (int rt = 0; rt < 4; ++rt)
#pragma unroll
      for (int r = 0; r < 4; ++r) {
        e[rt][r] = __expf(sc[rt][r] - m);
        s += e[rt][r];
      }
    s += __shfl_xor(s, 16);
    s += __shfl_xor(s, 32);
    float inv = 1.0f / s;
    float* ao = attn_out + ((size_t)bb * NA + 16 * wv + c) * NA;
#pragma unroll
    for (int rt = 0; rt < 4; ++rt) {
      f32x4 vv;
#pragma unroll
      for (int r = 0; r < 4; ++r) vv[r] = e[rt][r] * inv;
      *(f32x4*)(ao + 16 * rt + 4 * g) = vv;
#pragma unroll
      for (int r = 0; r < 4; ++r) stATT_val(rt, r, vv[r]);
    }
  }
  __syncthreads();  // B4: emb reads done; ATT complete
  // ====== P5: xg1 = x@gc1+b -> R0 (B-packed, over emb) ======
  {
    f32x4 acc[4][4]{};
    mm_x(acc, wp + W_GC1);
#pragma unroll
    for (int nt = 0; nt < 4; ++nt) {
      float bv = b_gc1[64 * wv + 16 * nt + c];
#pragma unroll
      for (int rt = 0; rt < 4; ++rt)
#pragma unroll
        for (int r = 0; r < 4; ++r)
          stB_val(R0, rt, nt, r, acc[rt][nt][r] + bv);
    }
  }
  __syncthreads();  // B5
  // ====== P6: feat = (relu(attn@xg1) + relu(x@nn1+b))/64 -> R0 (A-packed) ======
  {
    f32x4 a2[4][4]{};
    mm_x(a2, wp + W_NN1);
    _Float16 r2h[4][4][4];  // finalize nn1 branch to fp16, free the acc
#pragma unroll
    for (int nt = 0; nt < 4; ++nt) {
      float bv = b_nn1[64 * wv + 16 * nt + c];
#pragma unroll
      for (int rt = 0; rt < 4; ++rt)
#pragma unroll
        for (int r = 0; r < 4; ++r)
          r2h[rt][nt][r] = (_Float16)fmaxf(a2[rt][nt][r] + bv, 0.f);
    }
    f32x4 a1[4][4]{};
    mm_att(a1);
    __syncthreads();  // B6: xg1T reads done
#pragma unroll
    for (int nt = 0; nt < 4; ++nt)
#pragma unroll
      for (int rt = 0; rt < 4; ++rt)
#pragma unroll
        for (int r = 0; r < 4; ++r)
          stA_val(R0, rt, nt, r,
                  (fmaxf(a1[rt][nt][r], 0.f) + (float)r2h[rt][nt][r]) * 0.015625f);
  }
  __syncthreads();  // B7
  // ====== P7+P8: nn2 branch, fg2 = feat@gc2+b -> B-packed, out ======
  {
    f32x4 a2[4][4]{};
    mmA(a2, R0, wp + W_NN2, 8);
    _Float16 r2h[4][4][4];
#pragma unroll
    for (int nt = 0; nt < 4; ++nt) {
      float bv = b_nn2[64 * wv + 16 * nt + c];
#pragma unroll
      for (int rt = 0; rt < 4; ++rt)
#pragma unroll
        for (int r = 0; r < 4; ++r)
          r2h[rt][nt][r] = (_Float16)fmaxf(a2[rt][nt][r] + bv, 0.f);
    }
    f32x4 ag[4][4]{};
    mmA(ag, R0, wp + W_GC2, 8);
    __syncthreads();  // B8: all feat reads done
#pragma unroll
    for (int nt = 0; nt < 4; ++nt) {
      float bv = b_gc2[64 * wv + 16 * nt + c];
#pragma unroll
      for (int rt = 0; rt < 4; ++rt)
#pragma unroll
        for (int r = 0; r < 4; ++r)
          stB_val(R0, rt, nt, r, ag[rt][nt][r] + bv);
    }
    __syncthreads();  // B9
    f32x4 a1[4][4]{};
    mm_att(a1);
    float* ob = out + (size_t)bb * NA * HID;
#pragma unroll
    for (int nt = 0; nt < 4; ++nt)
#pragma unroll
      for (int rt = 0; rt < 4; ++rt)
#pragma unroll
        for (int r = 0; r < 4; ++r)
          ob[(size_t)(16 * rt + 4 * g + r) * HID + 64 * wv + 16 * nt + c] =
              (fmaxf(a1[rt][nt][r], 0.f) + (float)r2h[rt][nt][r]) * 0.015625f;
  }
}

extern "C" void kernel_launch(void* const* d_in, const int* in_sizes, int n_in,
                              void* d_out, int out_size, void* d_ws, size_t ws_size,
                              hipStream_t stream) {
  const float* x = (const float*)d_in[0];
  const float* enc_w1 = (const float*)d_in[1];
  const float* enc_b1 = (const float*)d_in[2];
  const float* enc_w2 = (const float*)d_in[3];
  const float* enc_b2 = (const float*)d_in[4];
  const float* attn_w = (const float*)d_in[5];
  const float* gc1_w = (const float*)d_in[6];
  const float* gc1_b = (const float*)d_in[7];
  const float* nn1_w = (const float*)d_in[8];
  const float* nn1_b = (const float*)d_in[9];
  const float* gc2_w = (const float*)d_in[10];
  const float* gc2_b = (const float*)d_in[11];
  const float* nn2_w = (const float*)d_in[12];
  const float* nn2_b = (const float*)d_in[13];
  // d_in[14] = n_agents (=64, compile-time constant)

  _Float16* wp = (_Float16*)d_ws;
  float* out = (float*)d_out;
  float* attn_o = out + (size_t)NBATCH * NA * HID;

  pack_all<<<176, 256, 0, stream>>>(enc_w1, enc_w2, attn_w, gc1_w, nn1_w, gc2_w,
                                    nn2_w, wp);
  dicg_main<<<NBATCH, 256, SMEM_BYTES, stream>>>(
      x, enc_b1, enc_b2, gc1_b, nn1_b, gc2_b, nn2_b, wp, out, attn_o);
}

// Round 4
// 167.522 us; speedup vs baseline: 1.4885x; 1.4885x over previous
//
#include <hip/hip_runtime.h>

typedef _Float16 half8 __attribute__((ext_vector_type(8)));
typedef _Float16 half4_t __attribute__((ext_vector_type(4)));
typedef float f32x4 __attribute__((ext_vector_type(4)));

#define NBATCH 2048
#define NA 64
#define SA 128
#define HID 256

// LDS halves: X 8192 (16KB) | R0 16384 (32KB) | ATT 8192 (16KB) = 65536 B
// ATT frags 0..7: attn A-frags; frags 8..15: per-wave q double-buffer slots.
#define OFF_X 0
#define OFF_R0 8192
#define OFF_ATT (8192 + 16384)
#define SMEM_BYTES ((8192 + 16384 + 8192) * 2)

// packed fp16 weight offsets (halves) inside d_ws
#define W_ENC1 0
#define W_ENC2 (W_ENC1 + 128 * 256)
#define W_ATTN (W_ENC2 + 256 * 256)
#define W_GC1 (W_ATTN + 256 * 256)
#define W_NN1 (W_GC1 + 128 * 256)
#define W_GC2 (W_NN1 + 128 * 256)
#define W_NN2 (W_GC2 + 256 * 256)

#define MFMA(a, b, cacc) __builtin_amdgcn_mfma_f32_16x16x32_f16((a), (b), (cacc), 0, 0, 0)

// One launch packs all 7 weights into MFMA B-fragment order fp16.
// dst[((kt*16+nt)*64+lane)*8 + j] = W[kt*32 + (lane>>4)*8 + j][nt*16 + (lane&15)]
__global__ void pack_all(const float* __restrict__ e1, const float* __restrict__ e2,
                         const float* __restrict__ aw, const float* __restrict__ g1,
                         const float* __restrict__ n1, const float* __restrict__ g2,
                         const float* __restrict__ n2, _Float16* __restrict__ dst) {
  int b = (int)blockIdx.x;
  const float* src;
  int off;
  if (b < 16) { src = e1; off = W_ENC1; }
  else if (b < 48) { src = e2; off = W_ENC2; b -= 16; }
  else if (b < 80) { src = aw; off = W_ATTN; b -= 48; }
  else if (b < 96) { src = g1; off = W_GC1; b -= 80; }
  else if (b < 112) { src = n1; off = W_NN1; b -= 96; }
  else if (b < 144) { src = g2; off = W_GC2; b -= 112; }
  else { src = n2; off = W_NN2; b -= 144; }
  int t = b * 256 + (int)threadIdx.x;
  int lane = t & 63, frag = t >> 6;
  int nt = frag & 15, kt = frag >> 4;
  int g = lane >> 4, c = lane & 15;
  half8 h;
#pragma unroll
  for (int j = 0; j < 8; ++j)
    h[j] = (_Float16)src[(size_t)(kt * 32 + g * 8 + j) * 256 + nt * 16 + c];
  *(half8*)(dst + off + (size_t)t * 8) = h;
}

__global__ __launch_bounds__(256, 2) void dicg_main(
    const float* __restrict__ x, const float* __restrict__ b_enc1,
    const float* __restrict__ b_enc2, const float* __restrict__ b_gc1,
    const float* __restrict__ b_nn1, const float* __restrict__ b_gc2,
    const float* __restrict__ b_nn2, const _Float16* __restrict__ wp,
    float* __restrict__ out, float* __restrict__ attn_out) {
  extern __shared__ _Float16 sm[];
  _Float16* X = sm + OFF_X;        // x fp16 A-frags (written P1, read P5/P6)
  _Float16* R0 = sm + OFF_R0;      // h1 -> emb -> xg1T -> feat -> fg2T
  _Float16* ATTp = sm + OFF_ATT;   // frags 0..7: attn A-frags; 8..15: q dbuf slots

  const int tid = (int)threadIdx.x;
  const int wv = tid >> 6;   // wave 0..3 (owns output cols 64*wv..+63)
  const int lane = tid & 63;
  const int g = lane >> 4;   // 0..3
  const int c = lane & 15;   // 0..15
  const int bb = (int)blockIdx.x;
  const float* __restrict__ xb = x + (size_t)bb * (NA * SA);

  // ---- fragment-linear LDS loads (conflict-free: lane*16B contiguous) ----
  auto ldA = [&](const _Float16* p, int kt, int rt) -> half8 {
    return *(const half8*)(p + (kt * 4 + rt) * 512 + lane * 8);
  };
  auto ldB = [&](const _Float16* p, int kt, int ct) -> half8 {
    return *(const half8*)(p + (kt * 16 + ct) * 512 + lane * 8);
  };
  auto wfrag = [&](const _Float16* wb, int kt, int ntg) -> half8 {
    return *(const half8*)(wb + ((size_t)(kt * 16 + ntg) * 64 + lane) * 8);
  };
  auto xfrag = [&](int r0, int k0) -> half8 {
    const float* p = xb + (r0 + c) * SA + k0 + g * 8;
    f32x4 u = *(const f32x4*)p;
    f32x4 v = *(const f32x4*)(p + 4);
    half8 h;
    h[0] = (_Float16)u[0]; h[1] = (_Float16)u[1];
    h[2] = (_Float16)u[2]; h[3] = (_Float16)u[3];
    h[4] = (_Float16)v[0]; h[5] = (_Float16)v[1];
    h[6] = (_Float16)v[2]; h[7] = (_Float16)v[3];
    return h;
  };

  // ---- C-layout -> packed-LDS stores ----
  // producer lane holds D[16rt+4g+r][64wv+16nt+c]
  auto stA_val = [&](_Float16* dst, int rt, int nt, int r, float v) {
    int kt = 2 * wv + (nt >> 1);
    int lanep = (2 * (nt & 1) + (c >> 3)) * 16 + 4 * g + r;
    dst[(kt * 4 + rt) * 512 + lanep * 8 + (c & 7)] = (_Float16)v;
  };
  auto ep_storeA = [&](f32x4(&acc)[4][4], const float* bias, bool dorelu) {
#pragma unroll
    for (int nt = 0; nt < 4; ++nt) {
      float bv = bias[64 * wv + 16 * nt + c];
#pragma unroll
      for (int rt = 0; rt < 4; ++rt)
#pragma unroll
        for (int r = 0; r < 4; ++r) {
          float y = acc[rt][nt][r] + bv;
          if (dorelu) y = fmaxf(y, 0.f);
          stA_val(R0, rt, nt, r, y);
        }
    }
  };
  // B-packed store, vectorized: 4 consecutive halves per (rt,nt)
  auto ep_storeB = [&](f32x4(&acc)[4][4], const float* bias) {
#pragma unroll
    for (int nt = 0; nt < 4; ++nt) {
      float bv = bias[64 * wv + 16 * nt + c];
#pragma unroll
      for (int rt = 0; rt < 4; ++rt) {
        half4_t h;
#pragma unroll
        for (int r = 0; r < 4; ++r) h[r] = (_Float16)(acc[rt][nt][r] + bv);
        int fi = (rt >> 1) * 16 + 4 * wv + nt;
        int lanep = (2 * (rt & 1) + (g >> 1)) * 16 + c;
        *(half4_t*)(R0 + fi * 512 + lanep * 8 + 4 * (g & 1)) = h;
      }
    }
  };
  // q chunk C-layout -> per-wave double-buffered B-frag scratch (frags 8..15)
  auto stQ = [&](const f32x4(&q2)[2], int s) {
    _Float16* base = ATTp + (8 + 2 * wv + s) * 512;
#pragma unroll
    for (int nt2 = 0; nt2 < 2; ++nt2)
#pragma unroll
      for (int r = 0; r < 4; ++r)
        base[((2 * nt2 + (c >> 3)) * 16 + 4 * g + r) * 8 + (c & 7)] = (_Float16)q2[nt2][r];
  };

  auto mmA = [&](f32x4(&acc)[4][4], const _Float16* Ap, const _Float16* wb, int nkt) {
#pragma unroll
    for (int kt = 0; kt < nkt; ++kt) {
      half8 af[4], bf[4];
#pragma unroll
      for (int rt = 0; rt < 4; ++rt) af[rt] = ldA(Ap, kt, rt);
#pragma unroll
      for (int nt = 0; nt < 4; ++nt) bf[nt] = wfrag(wb, kt, 4 * wv + nt);
#pragma unroll
      for (int rt = 0; rt < 4; ++rt)
#pragma unroll
        for (int nt = 0; nt < 4; ++nt) acc[rt][nt] = MFMA(af[rt], bf[nt], acc[rt][nt]);
    }
  };
  // fused: two weight matrices sharing the same A-frags
  auto mmA2 = [&](f32x4(&a1)[4][4], f32x4(&a2)[4][4], const _Float16* Ap,
                  const _Float16* wb1, const _Float16* wb2, int nkt) {
#pragma unroll
    for (int kt = 0; kt < nkt; ++kt) {
      half8 af[4], b1[4], b2[4];
#pragma unroll
      for (int rt = 0; rt < 4; ++rt) af[rt] = ldA(Ap, kt, rt);
#pragma unroll
      for (int nt = 0; nt < 4; ++nt) b1[nt] = wfrag(wb1, kt, 4 * wv + nt);
#pragma unroll
      for (int nt = 0; nt < 4; ++nt) b2[nt] = wfrag(wb2, kt, 4 * wv + nt);
#pragma unroll
      for (int rt = 0; rt < 4; ++rt)
#pragma unroll
        for (int nt = 0; nt < 4; ++nt) {
          a1[rt][nt] = MFMA(af[rt], b1[nt], a1[rt][nt]);
          a2[rt][nt] = MFMA(af[rt], b2[nt], a2[rt][nt]);
        }
    }
  };
  auto mm_att = [&](f32x4(&acc)[4][4]) {
#pragma unroll
    for (int kt = 0; kt < 2; ++kt) {
      half8 af[4], bf[4];
#pragma unroll
      for (int rt = 0; rt < 4; ++rt) af[rt] = ldA(ATTp, kt, rt);
#pragma unroll
      for (int nt = 0; nt < 4; ++nt) bf[nt] = ldB(R0, kt, 4 * wv + nt);
#pragma unroll
      for (int rt = 0; rt < 4; ++rt)
#pragma unroll
        for (int nt = 0; nt < 4; ++nt) acc[rt][nt] = MFMA(af[rt], bf[nt], acc[rt][nt]);
    }
  };

  // ========== P1: h1 = relu(x@enc1+b1) -> R0; stage x fp16 frags -> X ==========
  {
    f32x4 acc[4][4]{};
#pragma unroll
    for (int kt = 0; kt < 4; ++kt) {
      half8 af[4], bf[4];
#pragma unroll
      for (int rt = 0; rt < 4; ++rt) af[rt] = xfrag(16 * rt, kt * 32);
#pragma unroll
      for (int nt = 0; nt < 4; ++nt) bf[nt] = wfrag(wp + W_ENC1, kt, 4 * wv + nt);
      if (kt == wv) {  // each wave stages one kt of x (no redundant writes)
#pragma unroll
        for (int rt = 0; rt < 4; ++rt)
          *(half8*)(X + (kt * 4 + rt) * 512 + lane * 8) = af[rt];
      }
#pragma unroll
      for (int rt = 0; rt < 4; ++rt)
#pragma unroll
        for (int nt = 0; nt < 4; ++nt) acc[rt][nt] = MFMA(af[rt], bf[nt], acc[rt][nt]);
    }
    ep_storeA(acc, b_enc1, true);
  }
  __syncthreads();  // B1
  // ========== P2: emb = relu(h1@enc2+b2), in-place ==========
  {
    f32x4 acc[4][4]{};
    mmA(acc, R0, wp + W_ENC2, 8);
    __syncthreads();  // B2: all h1 reads done
    ep_storeA(acc, b_enc2, true);
  }
  __syncthreads();  // B3
  // ===== P3+P4: scoresT = emb @ qT (q dbuf-pipelined), softmax =====
  {
    half8 aeK[8];
#pragma unroll
    for (int k2 = 0; k2 < 8; ++k2) aeK[k2] = ldA(R0, k2, wv);
    f32x4 sc[4]{};
    {
      f32x4 q2[2]{};
#pragma unroll
      for (int k2 = 0; k2 < 8; ++k2) {
        q2[0] = MFMA(aeK[k2], wfrag(wp + W_ATTN, k2, 0), q2[0]);
        q2[1] = MFMA(aeK[k2], wfrag(wp + W_ATTN, k2, 1), q2[1]);
      }
      stQ(q2, 0);
    }
#pragma unroll
    for (int ktp = 0; ktp < 8; ++ktp) {
      f32x4 q2n[2]{};
      if (ktp < 7) {  // compute next q chunk BEFORE the wall (covers store latency)
#pragma unroll
        for (int k2 = 0; k2 < 8; ++k2) {
          q2n[0] = MFMA(aeK[k2], wfrag(wp + W_ATTN, k2, 2 * ktp + 2), q2n[0]);
          q2n[1] = MFMA(aeK[k2], wfrag(wp + W_ATTN, k2, 2 * ktp + 3), q2n[1]);
        }
      }
      asm volatile("s_waitcnt lgkmcnt(0)" ::: "memory");
      half8 qb = *(const half8*)(ATTp + (8 + 2 * wv + (ktp & 1)) * 512 + lane * 8);
      if (ktp < 7) stQ(q2n, (ktp + 1) & 1);
#pragma unroll
      for (int rt = 0; rt < 4; ++rt) sc[rt] = MFMA(ldA(R0, ktp, rt), qb, sc[rt]);
    }
    // softmax over row (16wv+c), spread across lanes {g*16+c}
    float m = sc[0][0];
#pragma unroll
    for (int rt = 0; rt < 4; ++rt)
#pragma unroll
      for (int r = 0; r < 4; ++r) m = fmaxf(m, sc[rt][r]);
    m = fmaxf(m, __shfl_xor(m, 16));
    m = fmaxf(m, __shfl_xor(m, 32));
    float e[4][4], s = 0.f;
#pragma unroll
    for (int rt = 0; rt < 4; ++rt)
#pragma unroll
      for (int r = 0; r < 4; ++r) {
        e[rt][r] = __expf(sc[rt][r] - m);
        s += e[rt][r];
      }
    s += __shfl_xor(s, 16);
    s += __shfl_xor(s, 32);
    float inv = 1.0f / s;
    float* ao = attn_out + ((size_t)bb * NA + 16 * wv + c) * NA;
#pragma unroll
    for (int rt = 0; rt < 4; ++rt) {
      f32x4 vv;
      half4_t hh;
#pragma unroll
      for (int r = 0; r < 4; ++r) {
        vv[r] = e[rt][r] * inv;
        hh[r] = (_Float16)vv[r];
      }
      *(f32x4*)(ao + 16 * rt + 4 * g) = vv;
      int fi = (rt >> 1) * 4 + wv;
      int lanep = (2 * (rt & 1) + (g >> 1)) * 16 + c;
      *(half4_t*)(ATTp + fi * 512 + lanep * 8 + 4 * (g & 1)) = hh;
    }
  }
  __syncthreads();  // B4: emb reads done; ATT frags 0..7 complete
  // ===== P5+P6 fused pass over x: xg1 = x@gc1+b, nn1 = relu(x@nn1+b) =====
  {
    f32x4 aG[4][4]{}, aN[4][4]{};
    mmA2(aG, aN, X, wp + W_GC1, wp + W_NN1, 4);
    ep_storeB(aG, b_gc1);  // xg1 -> R0 (over emb; safe after B4)
    half4_t r2h[4][4];
#pragma unroll
    for (int nt = 0; nt < 4; ++nt) {
      float bv = b_nn1[64 * wv + 16 * nt + c];
#pragma unroll
      for (int rt = 0; rt < 4; ++rt)
#pragma unroll
        for (int r = 0; r < 4; ++r)
          r2h[rt][nt][r] = (_Float16)fmaxf(aN[rt][nt][r] + bv, 0.f);
    }
    __syncthreads();  // B5: xg1 visible to all waves
    f32x4 a1[4][4]{};
    mm_att(a1);
    __syncthreads();  // B6: all xg1 reads done
#pragma unroll
    for (int nt = 0; nt < 4; ++nt)
#pragma unroll
      for (int rt = 0; rt < 4; ++rt)
#pragma unroll
        for (int r = 0; r < 4; ++r)
          stA_val(R0, rt, nt, r,
                  (fmaxf(a1[rt][nt][r], 0.f) + (float)r2h[rt][nt][r]) * 0.015625f);
  }
  __syncthreads();  // B7: feat complete
  // ===== P7+P8 fused pass over feat: nn2 branch + fg2 = feat@gc2+b, out =====
  {
    f32x4 aN[4][4]{}, aG[4][4]{};
    mmA2(aN, aG, R0, wp + W_NN2, wp + W_GC2, 8);
    half4_t r2h[4][4];
#pragma unroll
    for (int nt = 0; nt < 4; ++nt) {
      float bv = b_nn2[64 * wv + 16 * nt + c];
#pragma unroll
      for (int rt = 0; rt < 4; ++rt)
#pragma unroll
        for (int r = 0; r < 4; ++r)
          r2h[rt][nt][r] = (_Float16)fmaxf(aN[rt][nt][r] + bv, 0.f);
    }
    __syncthreads();  // B8: all feat reads done
    ep_storeB(aG, b_gc2);  // fg2 -> R0
    __syncthreads();  // B9
    f32x4 a1[4][4]{};
    mm_att(a1);
    float* ob = out + (size_t)bb * NA * HID;
#pragma unroll
    for (int nt = 0; nt < 4; ++nt)
#pragma unroll
      for (int rt = 0; rt < 4; ++rt)
#pragma unroll
        for (int r = 0; r < 4; ++r)
          ob[(size_t)(16 * rt + 4 * g + r) * HID + 64 * wv + 16 * nt + c] =
              (fmaxf(a1[rt][nt][r], 0.f) + (float)r2h[rt][nt][r]) * 0.015625f;
  }
}

extern "C" void kernel_launch(void* const* d_in, const int* in_sizes, int n_in,
                              void* d_out, int out_size, void* d_ws, size_t ws_size,
                              hipStream_t stream) {
  const float* x = (const float*)d_in[0];
  const float* enc_w1 = (const float*)d_in[1];
  const float* enc_b1 = (const float*)d_in[2];
  const float* enc_w2 = (const float*)d_in[3];
  const float* enc_b2 = (const float*)d_in[4];
  const float* attn_w = (const float*)d_in[5];
  const float* gc1_w = (const float*)d_in[6];
  const float* gc1_b = (const float*)d_in[7];
  const float* nn1_w = (const float*)d_in[8];
  const float* nn1_b = (const float*)d_in[9];
  const float* gc2_w = (const float*)d_in[10];
  const float* gc2_b = (const float*)d_in[11];
  const float* nn2_w = (const float*)d_in[12];
  const float* nn2_b = (const float*)d_in[13];
  // d_in[14] = n_agents (=64, compile-time constant)

  _Float16* wp = (_Float16*)d_ws;
  float* out = (float*)d_out;
  float* attn_o = out + (size_t)NBATCH * NA * HID;

  pack_all<<<176, 256, 0, stream>>>(enc_w1, enc_w2, attn_w, gc1_w, nn1_w, gc2_w,
                                    nn2_w, wp);
  dicg_main<<<NBATCH, 256, SMEM_BYTES, stream>>>(
      x, enc_b1, enc_b2, gc1_b, nn1_b, gc2_b, nn2_b, wp, out, attn_o);
}